// Round 1
// baseline (21691.212 us; speedup 1.0000x reference)
//
#include <hip/hip_runtime.h>

#define BATCH   16384
#define NSTEPS  100
#define DT_     0.01f
#define SQRTDT  0.1f
#define SIGMA0_ 0.5f

__global__ void zero_out_kernel(float* out) {
    if (threadIdx.x == 0) out[0] = 0.0f;
}

// Computes one MLP (2 -> 64 -> 64 -> C) for this thread's path, with this
// thread owning hidden-2 neurons [jb, jb+16). Layer-3 partials are reduced
// across the 4 sub-lanes of the path (shfl_xor 1,2) so ALL 4 lanes return
// the full output vector o[C] (bias included).
template<int C>
__device__ __forceinline__ void mlp4(const float* __restrict__ sW1,
                                     const float* __restrict__ sB1,
                                     const float* __restrict__ sW2,
                                     const float* __restrict__ sB2,
                                     const float* __restrict__ sW3,
                                     const float* __restrict__ sB3,
                                     float t, float y, int jb, float* o)
{
    // layer 1: h1[k] = relu(W1[0][k]*t + W1[1][k]*y + b1[k])  (redundant per sub-lane)
    float h1[64];
#pragma unroll
    for (int k = 0; k < 64; ++k)
        h1[k] = fmaxf(0.0f, fmaf(sW1[k], t, fmaf(sW1[64 + k], y, sB1[k])));

    // layer 2: 16 owned output neurons, 16 independent FMA chains for ILP
    float a2[16];
#pragma unroll
    for (int j = 0; j < 16; ++j) a2[j] = sB2[jb + j];

#pragma unroll
    for (int k = 0; k < 64; ++k) {
        float hk = h1[k];
        const float4* wr = (const float4*)(sW2 + k * 64 + jb);  // 64B-aligned
        float4 w0 = wr[0], w1 = wr[1], w2 = wr[2], w3 = wr[3];
        a2[0]  = fmaf(hk, w0.x, a2[0]);
        a2[1]  = fmaf(hk, w0.y, a2[1]);
        a2[2]  = fmaf(hk, w0.z, a2[2]);
        a2[3]  = fmaf(hk, w0.w, a2[3]);
        a2[4]  = fmaf(hk, w1.x, a2[4]);
        a2[5]  = fmaf(hk, w1.y, a2[5]);
        a2[6]  = fmaf(hk, w1.z, a2[6]);
        a2[7]  = fmaf(hk, w1.w, a2[7]);
        a2[8]  = fmaf(hk, w2.x, a2[8]);
        a2[9]  = fmaf(hk, w2.y, a2[9]);
        a2[10] = fmaf(hk, w2.z, a2[10]);
        a2[11] = fmaf(hk, w2.w, a2[11]);
        a2[12] = fmaf(hk, w3.x, a2[12]);
        a2[13] = fmaf(hk, w3.y, a2[13]);
        a2[14] = fmaf(hk, w3.z, a2[14]);
        a2[15] = fmaf(hk, w3.w, a2[15]);
    }

    // layer 3 partial over owned neurons, then 4-lane butterfly reduce
    float oc[C];
#pragma unroll
    for (int c = 0; c < C; ++c) oc[c] = 0.0f;
#pragma unroll
    for (int j = 0; j < 16; ++j) {
        float h = fmaxf(0.0f, a2[j]);
        const float* w3r = sW3 + (jb + j) * C;
#pragma unroll
        for (int c = 0; c < C; ++c) oc[c] = fmaf(h, w3r[c], oc[c]);
    }
#pragma unroll
    for (int c = 0; c < C; ++c) {
        float v = oc[c];
        v += __shfl_xor(v, 1);
        v += __shfl_xor(v, 2);
        o[c] = v + sB3[c];
    }
}

__launch_bounds__(256)
__global__ void deepbsde_kernel(
    const float* __restrict__ y0,  const float* __restrict__ Y0,
    const float* __restrict__ zW1, const float* __restrict__ zb1,
    const float* __restrict__ zW2, const float* __restrict__ zb2,
    const float* __restrict__ zW3, const float* __restrict__ zb3,
    const float* __restrict__ qW1, const float* __restrict__ qb1,
    const float* __restrict__ qW2, const float* __restrict__ qb2,
    const float* __restrict__ qW3, const float* __restrict__ qb3,
    const float* __restrict__ dW,  const float* __restrict__ dZ,
    float* __restrict__ out)
{
    __shared__ __align__(16) float sZW1[128];
    __shared__ float sZB1[64];
    __shared__ __align__(16) float sZW2[64 * 64];
    __shared__ float sZB2[64];
    __shared__ float sZW3[64 * 3];
    __shared__ float sZB3[3];
    __shared__ __align__(16) float sQW1[128];
    __shared__ float sQB1[64];
    __shared__ __align__(16) float sQW2[64 * 64];
    __shared__ float sQB2[64];
    __shared__ float sQW3[64];
    __shared__ float sQB3[1];
    __shared__ float red[4];

    const int tid = threadIdx.x;
#define CPY(d, s, n) for (int i_ = tid; i_ < (n); i_ += 256) d[i_] = s[i_]
    CPY(sZW1, zW1, 128);  CPY(sZB1, zb1, 64);
    CPY(sZW2, zW2, 4096); CPY(sZB2, zb2, 64);
    CPY(sZW3, zW3, 192);  CPY(sZB3, zb3, 3);
    CPY(sQW1, qW1, 128);  CPY(sQB1, qb1, 64);
    CPY(sQW2, qW2, 4096); CPY(sQB2, qb2, 64);
    CPY(sQW3, qW3, 64);   CPY(sQB3, qb3, 1);
#undef CPY
    __syncthreads();

    const int sub = tid & 3;          // which 16-neuron slice of hidden-2
    const int jb  = sub << 4;
    const int p   = (blockIdx.x << 6) + (tid >> 2);   // global path id

    float y   = y0[0];
    float Yv  = Y0[0];
    float t   = 0.0f;
    float acc = 0.0f;

    const float* dWp = dW + (size_t)p * 3;
    const float* dZp = dZ + (size_t)p * 3;

#pragma unroll 1
    for (int i = 0; i < NSTEPS; ++i) {
        // issue noise loads early; not needed until after the MLPs
        float w0 = dWp[0], w1 = dWp[1], w2 = dWp[2];
        float x0 = dZp[0], x1 = dZp[1], x2 = dZp[2];
        dWp += (size_t)BATCH * 3;
        dZp += (size_t)BATCH * 3;

        float zout[3];
        mlp4<3>(sZW1, sZB1, sZW2, sZB2, sZW3, sZB3, t, y, jb, zout);
        float qout[1];
        mlp4<1>(sQW1, sQB1, sQW2, sQB2, sQW3, sQB3, t, y, jb, qout);
        float q = qout[0];

        float dw0 = SQRTDT * w0, dw1 = SQRTDT * w1, dw2 = SQRTDT * w2;
        float dz0 = SQRTDT * x0, dz1 = SQRTDT * x1, dz2 = SQRTDT * x2;

        float zdw = zout[0] * dw0 + zout[1] * dw1 + zout[2] * dw2;
        float zdz = zout[0] * dz0 + zout[1] * dz1 + zout[2] * dz2;

        float f = 0.5f * q * q;
        float Ynext = Yv - f * DT_ + zdw;
        float r = zdw - zdz;           // residual (Y - f*DT terms cancel)
        acc = fmaf(r, r, acc);

        y  = y + q * DT_ + SIGMA0_ * (dw0 + dw1 + dw2);
        Yv = Ynext;
        t += DT_;
    }

    float d = Yv - y * y;              // terminal contribution
    acc = fmaf(d, d, acc);

    // 4 sub-lanes hold identical acc -> count once
    float val = (sub == 0) ? acc : 0.0f;
#pragma unroll
    for (int off = 1; off < 64; off <<= 1) val += __shfl_xor(val, off);
    if ((tid & 63) == 0) red[tid >> 6] = val;
    __syncthreads();
    if (tid == 0) {
        float s = (red[0] + red[1] + red[2] + red[3]) * (1.0f / BATCH);
        atomicAdd(out, s);
    }
}

extern "C" void kernel_launch(void* const* d_in, const int* in_sizes, int n_in,
                              void* d_out, int out_size, void* d_ws, size_t ws_size,
                              hipStream_t stream)
{
    zero_out_kernel<<<1, 64, 0, stream>>>((float*)d_out);
    deepbsde_kernel<<<256, 256, 0, stream>>>(
        (const float*)d_in[0],  (const float*)d_in[1],
        (const float*)d_in[2],  (const float*)d_in[3],
        (const float*)d_in[4],  (const float*)d_in[5],
        (const float*)d_in[6],  (const float*)d_in[7],
        (const float*)d_in[8],  (const float*)d_in[9],
        (const float*)d_in[10], (const float*)d_in[11],
        (const float*)d_in[12], (const float*)d_in[13],
        (const float*)d_in[14], (const float*)d_in[15],
        (float*)d_out);
}

// Round 2
// 918.459 us; speedup vs baseline: 23.6170x; 23.6170x over previous
//
#include <hip/hip_runtime.h>

#define BATCH   16384
#define NSTEPS  100
#define DT_     0.01f
#define SQRTDT  0.1f
#define SIGMA0_ 0.5f

__global__ void zero_out_kernel(float* out) {
    if (threadIdx.x == 0) out[0] = 0.0f;
}

__device__ __forceinline__ float red8(float v) {
    v += __shfl_xor(v, 1);
    v += __shfl_xor(v, 2);
    v += __shfl_xor(v, 4);
    return v;
}

// Thread layout: lane L -> sub = L&7 (owns hidden-2 neurons [8*sub, 8*sub+8)),
// pathgroup = L>>3. Each thread handles M=2 paths. 256 blocks x 256 threads
// = 1024 waves = 1 wave/SIMD across all 256 CUs. No h1 array: layer-1 is
// recomputed per k inside the layer-2 loop (input is only (t,y)).
__launch_bounds__(256)
__global__ void deepbsde_kernel(
    const float* __restrict__ y0,  const float* __restrict__ Y0,
    const float* __restrict__ zW1, const float* __restrict__ zb1,
    const float* __restrict__ zW2, const float* __restrict__ zb2,
    const float* __restrict__ zW3, const float* __restrict__ zb3,
    const float* __restrict__ qW1, const float* __restrict__ qb1,
    const float* __restrict__ qW2, const float* __restrict__ qb2,
    const float* __restrict__ qW3, const float* __restrict__ qb3,
    const float* __restrict__ dW,  const float* __restrict__ dZ,
    float* __restrict__ out)
{
    // layer-1 params packed (A=W1[0][k], B=W1[1][k], C=b1[k], 0)
    __shared__ float4 sZP[64];
    __shared__ float4 sQP[64];
    __shared__ __align__(16) float sZW2[64 * 64];
    __shared__ __align__(16) float sQW2[64 * 64];
    // layer-3 packed per hidden-2 neuron j: (zW3[j][0], zW3[j][1], zW3[j][2], qW3[j])
    __shared__ float4 sW3[64];
    __shared__ float red[4];

    const int tid = threadIdx.x;

    // ---- stage weights into LDS ----
    {
        const float4* s1 = (const float4*)zW2;
        const float4* s2 = (const float4*)qW2;
        float4* p1 = (float4*)sZW2;
        float4* p2 = (float4*)sQW2;
        for (int i = tid; i < 1024; i += 256) { p1[i] = s1[i]; p2[i] = s2[i]; }
        if (tid < 64) {
            sZP[tid] = make_float4(zW1[tid], zW1[64 + tid], zb1[tid], 0.0f);
            sQP[tid] = make_float4(qW1[tid], qW1[64 + tid], qb1[tid], 0.0f);
            sW3[tid] = make_float4(zW3[tid * 3 + 0], zW3[tid * 3 + 1],
                                   zW3[tid * 3 + 2], qW3[tid]);
        }
    }
    __syncthreads();

    const int sub = tid & 7;
    const int jb  = sub << 3;                 // owned neuron base
    const int slot = tid >> 3;                // 0..31 within block
    const int p0 = (blockIdx.x << 6) + slot;  // path 0
    const int p1 = p0 + 32;                   // path 1

    // constants held in registers across the whole loop
    float zb2r[8], qb2r[8];
#pragma unroll
    for (int j = 0; j < 8; ++j) { zb2r[j] = zb2[jb + j]; qb2r[j] = qb2[jb + j]; }
    const float zb3r0 = zb3[0], zb3r1 = zb3[1], zb3r2 = zb3[2], qb3r = qb3[0];

    float y[2], Yv[2];
    y[0] = y[1] = y0[0];
    Yv[0] = Yv[1] = Y0[0];
    float t = 0.0f;
    float acc = 0.0f;

    const float* dW0 = dW + (size_t)p0 * 3;
    const float* dW1 = dW + (size_t)p1 * 3;
    const float* dZ0 = dZ + (size_t)p0 * 3;
    const float* dZ1 = dZ + (size_t)p1 * 3;

#pragma unroll 1
    for (int i = 0; i < NSTEPS; ++i) {
        // noise loads issued early, consumed at the end of the body
        float nw[2][3], nz[2][3];
#pragma unroll
        for (int c = 0; c < 3; ++c) {
            nw[0][c] = dW0[c]; nw[1][c] = dW1[c];
            nz[0][c] = dZ0[c]; nz[1][c] = dZ1[c];
        }
        dW0 += (size_t)BATCH * 3; dW1 += (size_t)BATCH * 3;
        dZ0 += (size_t)BATCH * 3; dZ1 += (size_t)BATCH * 3;

        // ---- z-MLP layer 2 (layer 1 fused, recomputed per k) ----
        float za[2][8], qa[2][8];
#pragma unroll
        for (int j = 0; j < 8; ++j) { za[0][j] = zb2r[j]; za[1][j] = zb2r[j]; }
#pragma unroll
        for (int j = 0; j < 8; ++j) { qa[0][j] = qb2r[j]; qa[1][j] = qb2r[j]; }

#pragma unroll 8
        for (int k = 0; k < 64; ++k) {
            float4 pk = sZP[k];
            float v  = fmaf(pk.x, t, pk.z);
            float h0 = fmaxf(0.0f, fmaf(pk.y, y[0], v));
            float h1 = fmaxf(0.0f, fmaf(pk.y, y[1], v));
            const float4* wr = (const float4*)(sZW2 + k * 64 + jb);
            float4 w0 = wr[0], w1 = wr[1];
            za[0][0] = fmaf(h0, w0.x, za[0][0]);  za[1][0] = fmaf(h1, w0.x, za[1][0]);
            za[0][1] = fmaf(h0, w0.y, za[0][1]);  za[1][1] = fmaf(h1, w0.y, za[1][1]);
            za[0][2] = fmaf(h0, w0.z, za[0][2]);  za[1][2] = fmaf(h1, w0.z, za[1][2]);
            za[0][3] = fmaf(h0, w0.w, za[0][3]);  za[1][3] = fmaf(h1, w0.w, za[1][3]);
            za[0][4] = fmaf(h0, w1.x, za[0][4]);  za[1][4] = fmaf(h1, w1.x, za[1][4]);
            za[0][5] = fmaf(h0, w1.y, za[0][5]);  za[1][5] = fmaf(h1, w1.y, za[1][5]);
            za[0][6] = fmaf(h0, w1.z, za[0][6]);  za[1][6] = fmaf(h1, w1.z, za[1][6]);
            za[0][7] = fmaf(h0, w1.w, za[0][7]);  za[1][7] = fmaf(h1, w1.w, za[1][7]);
        }

        // ---- q-MLP layer 2 ----
#pragma unroll 8
        for (int k = 0; k < 64; ++k) {
            float4 pk = sQP[k];
            float v  = fmaf(pk.x, t, pk.z);
            float h0 = fmaxf(0.0f, fmaf(pk.y, y[0], v));
            float h1 = fmaxf(0.0f, fmaf(pk.y, y[1], v));
            const float4* wr = (const float4*)(sQW2 + k * 64 + jb);
            float4 w0 = wr[0], w1 = wr[1];
            qa[0][0] = fmaf(h0, w0.x, qa[0][0]);  qa[1][0] = fmaf(h1, w0.x, qa[1][0]);
            qa[0][1] = fmaf(h0, w0.y, qa[0][1]);  qa[1][1] = fmaf(h1, w0.y, qa[1][1]);
            qa[0][2] = fmaf(h0, w0.z, qa[0][2]);  qa[1][2] = fmaf(h1, w0.z, qa[1][2]);
            qa[0][3] = fmaf(h0, w0.w, qa[0][3]);  qa[1][3] = fmaf(h1, w0.w, qa[1][3]);
            qa[0][4] = fmaf(h0, w1.x, qa[0][4]);  qa[1][4] = fmaf(h1, w1.x, qa[1][4]);
            qa[0][5] = fmaf(h0, w1.y, qa[0][5]);  qa[1][5] = fmaf(h1, w1.y, qa[1][5]);
            qa[0][6] = fmaf(h0, w1.z, qa[0][6]);  qa[1][6] = fmaf(h1, w1.z, qa[1][6]);
            qa[0][7] = fmaf(h0, w1.w, qa[0][7]);  qa[1][7] = fmaf(h1, w1.w, qa[1][7]);
        }

        // ---- joint layer 3 over owned neurons, then 8-lane reduce ----
        float oz0[2] = {0, 0}, oz1[2] = {0, 0}, oz2[2] = {0, 0}, oq[2] = {0, 0};
#pragma unroll
        for (int j = 0; j < 8; ++j) {
            float4 w = sW3[jb + j];
#pragma unroll
            for (int p = 0; p < 2; ++p) {
                float hz = fmaxf(0.0f, za[p][j]);
                float hq = fmaxf(0.0f, qa[p][j]);
                oz0[p] = fmaf(hz, w.x, oz0[p]);
                oz1[p] = fmaf(hz, w.y, oz1[p]);
                oz2[p] = fmaf(hz, w.z, oz2[p]);
                oq[p]  = fmaf(hq, w.w, oq[p]);
            }
        }

#pragma unroll
        for (int p = 0; p < 2; ++p) {
            float z0 = red8(oz0[p]) + zb3r0;
            float z1 = red8(oz1[p]) + zb3r1;
            float z2 = red8(oz2[p]) + zb3r2;
            float q  = red8(oq[p])  + qb3r;

            float dw0 = SQRTDT * nw[p][0], dw1 = SQRTDT * nw[p][1], dw2 = SQRTDT * nw[p][2];
            float dz0 = SQRTDT * nz[p][0], dz1 = SQRTDT * nz[p][1], dz2 = SQRTDT * nz[p][2];

            float zdw = fmaf(z2, dw2, fmaf(z1, dw1, z0 * dw0));
            float zdz = fmaf(z2, dz2, fmaf(z1, dz1, z0 * dz0));

            float f = 0.5f * q * q;
            Yv[p] = Yv[p] - f * DT_ + zdw;
            float r = zdw - zdz;                 // residual: (Y - f*DT) cancels
            acc = fmaf(r, r, acc);
            y[p] = y[p] + q * DT_ + SIGMA0_ * (dw0 + dw1 + dw2);
        }
        t += DT_;
    }

#pragma unroll
    for (int p = 0; p < 2; ++p) {
        float d = Yv[p] - y[p] * y[p];
        acc = fmaf(d, d, acc);
    }

    // each path's acc is replicated on its 8 sub-lanes -> count sub==0 only
    float val = (sub == 0) ? acc : 0.0f;
#pragma unroll
    for (int off = 1; off < 64; off <<= 1) val += __shfl_xor(val, off);
    if ((tid & 63) == 0) red[tid >> 6] = val;
    __syncthreads();
    if (tid == 0) {
        float s = (red[0] + red[1] + red[2] + red[3]) * (1.0f / BATCH);
        atomicAdd(out, s);
    }
}

extern "C" void kernel_launch(void* const* d_in, const int* in_sizes, int n_in,
                              void* d_out, int out_size, void* d_ws, size_t ws_size,
                              hipStream_t stream)
{
    zero_out_kernel<<<1, 64, 0, stream>>>((float*)d_out);
    deepbsde_kernel<<<256, 256, 0, stream>>>(
        (const float*)d_in[0],  (const float*)d_in[1],
        (const float*)d_in[2],  (const float*)d_in[3],
        (const float*)d_in[4],  (const float*)d_in[5],
        (const float*)d_in[6],  (const float*)d_in[7],
        (const float*)d_in[8],  (const float*)d_in[9],
        (const float*)d_in[10], (const float*)d_in[11],
        (const float*)d_in[12], (const float*)d_in[13],
        (const float*)d_in[14], (const float*)d_in[15],
        (float*)d_out);
}

// Round 3
// 892.764 us; speedup vs baseline: 24.2967x; 1.0288x over previous
//
#include <hip/hip_runtime.h>

#define BATCH   16384
#define NSTEPS  100
#define DT_     0.01f
#define SQRTDT  0.1f
#define SIGMA0_ 0.5f

__global__ void zero_out_kernel(float* out) {
    if (threadIdx.x == 0) out[0] = 0.0f;
}

// Layout: lane (tid&63) owns one path; wave w = tid>>6 owns hidden-2 neuron
// slice [16w, 16w+16). All weight addresses are wave-uniform -> s_load (SMEM),
// weight FMAs read SGPR operands: no LDS / VMEM in the hot loop. The four
// waves' layer-3 partials combine through a 4KB LDS exchange per step.
// 256 blocks x 256 threads = 1024 waves = 1 wave/SIMD on all 256 CUs.
__launch_bounds__(256)
__global__ void deepbsde_kernel(
    const float* __restrict__ y0,  const float* __restrict__ Y0,
    const float* __restrict__ zW1, const float* __restrict__ zb1,
    const float* __restrict__ zW2, const float* __restrict__ zb2,
    const float* __restrict__ zW3, const float* __restrict__ zb3,
    const float* __restrict__ qW1, const float* __restrict__ qb1,
    const float* __restrict__ qW2, const float* __restrict__ qb2,
    const float* __restrict__ qW3, const float* __restrict__ qb3,
    const float* __restrict__ dW,  const float* __restrict__ dZ,
    float* __restrict__ out)
{
    __shared__ float4 part[4][64];

    const int tid  = threadIdx.x;
    const int lane = tid & 63;
    const int w    = tid >> 6;                                   // wave id 0..3
    const int jb   = __builtin_amdgcn_readfirstlane(w << 4);     // uniform j-base

    const int p = (blockIdx.x << 6) + lane;                      // path id

    // uniform slice pointers (SGPR arithmetic)
    const float* __restrict__ zw2p = zW2 + jb;   // zw2p[k*64 + j]
    const float* __restrict__ qw2p = qW2 + jb;
    const float* __restrict__ zw3p = zW3 + jb * 3;
    const float* __restrict__ qw3p = qW3 + jb;
    const float* __restrict__ zb2p = zb2 + jb;
    const float* __restrict__ qb2p = qb2 + jb;

    float y  = y0[0];
    float Yv = Y0[0];
    float t  = 0.0f;
    float acc = 0.0f;

    const float zb30 = zb3[0], zb31 = zb3[1], zb32 = zb3[2], qb30 = qb3[0];

    const float* dWp = dW + (size_t)p * 3;
    const float* dZp = dZ + (size_t)p * 3;

#pragma unroll 1
    for (int i = 0; i < NSTEPS; ++i) {
        float nw0 = dWp[0], nw1 = dWp[1], nw2 = dWp[2];
        float nz0 = dZp[0], nz1 = dZp[1], nz2 = dZp[2];
        dWp += (size_t)BATCH * 3;
        dZp += (size_t)BATCH * 3;

        float za[16], qa[16];
#pragma unroll
        for (int j = 0; j < 16; ++j) { za[j] = zb2p[j]; qa[j] = qb2p[j]; }

        // ---- z-MLP: fused layer1 (recomputed per k) + layer2 slice ----
#pragma unroll 4
        for (int k = 0; k < 64; ++k) {
            float hz = fmaxf(fmaf(zW1[64 + k], y, fmaf(zW1[k], t, zb1[k])), 0.0f);
            const float* __restrict__ wr = zw2p + k * 64;
#pragma unroll
            for (int j = 0; j < 16; ++j) za[j] = fmaf(hz, wr[j], za[j]);
        }

        // ---- q-MLP ----
#pragma unroll 4
        for (int k = 0; k < 64; ++k) {
            float hq = fmaxf(fmaf(qW1[64 + k], y, fmaf(qW1[k], t, qb1[k])), 0.0f);
            const float* __restrict__ wr = qw2p + k * 64;
#pragma unroll
            for (int j = 0; j < 16; ++j) qa[j] = fmaf(hq, wr[j], qa[j]);
        }

        // ---- layer-3 partials over owned j-slice ----
        float oz0 = 0.0f, oz1 = 0.0f, oz2 = 0.0f, oq = 0.0f;
#pragma unroll
        for (int j = 0; j < 16; ++j) {
            float hz = fmaxf(za[j], 0.0f);
            float hq = fmaxf(qa[j], 0.0f);
            oz0 = fmaf(hz, zw3p[j * 3 + 0], oz0);
            oz1 = fmaf(hz, zw3p[j * 3 + 1], oz1);
            oz2 = fmaf(hz, zw3p[j * 3 + 2], oz2);
            oq  = fmaf(hq, qw3p[j], oq);
        }

        // ---- combine the 4 waves' partials via LDS ----
        part[w][lane] = make_float4(oz0, oz1, oz2, oq);
        __syncthreads();
        float4 c0 = part[0][lane], c1 = part[1][lane];
        float4 c2 = part[2][lane], c3 = part[3][lane];
        __syncthreads();   // reads done before next step's writes

        float z0 = ((c0.x + c1.x) + (c2.x + c3.x)) + zb30;
        float z1 = ((c0.y + c1.y) + (c2.y + c3.y)) + zb31;
        float z2 = ((c0.z + c1.z) + (c2.z + c3.z)) + zb32;
        float q  = ((c0.w + c1.w) + (c2.w + c3.w)) + qb30;

        float dw0 = SQRTDT * nw0, dw1 = SQRTDT * nw1, dw2 = SQRTDT * nw2;
        float dz0 = SQRTDT * nz0, dz1 = SQRTDT * nz1, dz2 = SQRTDT * nz2;

        float zdw = fmaf(z2, dw2, fmaf(z1, dw1, z0 * dw0));
        float zdz = fmaf(z2, dz2, fmaf(z1, dz1, z0 * dz0));

        float f = 0.5f * q * q;
        Yv = Yv - f * DT_ + zdw;
        float r = zdw - zdz;            // residual: (Y - f*DT) cancels
        acc = fmaf(r, r, acc);          // identical in all 4 waves
        y = y + q * DT_ + SIGMA0_ * (dw0 + dw1 + dw2);
        t += DT_;
    }

    float d = Yv - y * y;
    acc = fmaf(d, d, acc);

    // only wave 0 contributes (all waves hold identical acc)
    if (w == 0) {
        float val = acc;
#pragma unroll
        for (int off = 1; off < 64; off <<= 1) val += __shfl_xor(val, off);
        if (lane == 0) atomicAdd(out, val * (1.0f / BATCH));
    }
}

extern "C" void kernel_launch(void* const* d_in, const int* in_sizes, int n_in,
                              void* d_out, int out_size, void* d_ws, size_t ws_size,
                              hipStream_t stream)
{
    zero_out_kernel<<<1, 64, 0, stream>>>((float*)d_out);
    deepbsde_kernel<<<256, 256, 0, stream>>>(
        (const float*)d_in[0],  (const float*)d_in[1],
        (const float*)d_in[2],  (const float*)d_in[3],
        (const float*)d_in[4],  (const float*)d_in[5],
        (const float*)d_in[6],  (const float*)d_in[7],
        (const float*)d_in[8],  (const float*)d_in[9],
        (const float*)d_in[10], (const float*)d_in[11],
        (const float*)d_in[12], (const float*)d_in[13],
        (const float*)d_in[14], (const float*)d_in[15],
        (float*)d_out);
}